// Round 3
// baseline (190.870 us; speedup 1.0000x reference)
//
#include <hip/hip_runtime.h>
#include <hip/hip_bf16.h>

typedef __attribute__((ext_vector_type(8))) unsigned short u16x8;
typedef __attribute__((ext_vector_type(4))) unsigned short u16x4;
typedef __attribute__((ext_vector_type(8))) short short8;
typedef __attribute__((ext_vector_type(4))) float floatx4;

#define BS 64
#define CIN 256
#define II 1024
#define OO 320
#define JJ 10
#define DD 32

__device__ __forceinline__ float b2f(unsigned short u) {
    union { unsigned int i; float f; } x; x.i = ((unsigned int)u) << 16; return x.f;
}
__device__ __forceinline__ unsigned short f2b(float f) {
    union { float f; unsigned int i; } x; x.f = f;
    unsigned int r = x.i + 0x7fffu + ((x.i >> 16) & 1u);
    return (unsigned short)(r >> 16);
}

// ---------------- K-1: convert W f32 -> bf16 ----------------
__global__ __launch_bounds__(256) void k_convW(const float* __restrict__ W,
                                               unsigned short* __restrict__ Wbf) {
    int idx = (blockIdx.x * 256 + threadIdx.x) * 4;
    float4 v = *(const float4*)(W + idx);
    u16x4 u;
    u[0] = f2b(v.x); u[1] = f2b(v.y); u[2] = f2b(v.z); u[3] = f2b(v.w);
    *(u16x4*)(Wbf + idx) = u;
}

// ---------------- K0: transpose+convert x[b][c][i] (f32) -> xt[b][i][c] (bf16) ----------------
__global__ __launch_bounds__(256) void k_transpose(const float* __restrict__ x,
                                                   unsigned short* __restrict__ xt) {
    __shared__ unsigned short tile[64][72];  // [c_local][i_local], +8 pad
    int i0 = blockIdx.x * 64, c0 = blockIdx.y * 64, b = blockIdx.z;
    int t = threadIdx.x;
    int row = t >> 3, col = (t & 7) * 8;
    const float* xb = x + ((size_t)b * CIN + c0) * II + i0;
#pragma unroll
    for (int r = 0; r < 2; ++r) {
        int rr = r * 32 + row;  // c_local
        float4 v0 = *(const float4*)(xb + (size_t)rr * II + col);
        float4 v1 = *(const float4*)(xb + (size_t)rr * II + col + 4);
        u16x8 u;
        u[0] = f2b(v0.x); u[1] = f2b(v0.y); u[2] = f2b(v0.z); u[3] = f2b(v0.w);
        u[4] = f2b(v1.x); u[5] = f2b(v1.y); u[6] = f2b(v1.z); u[7] = f2b(v1.w);
        *(u16x8*)&tile[rr][col] = u;
    }
    __syncthreads();
    unsigned short* xo = xt + ((size_t)b * II + i0) * CIN + c0;
#pragma unroll
    for (int r = 0; r < 2; ++r) {
        int rr = r * 32 + row;  // i_local
        u16x8 v;
#pragma unroll
        for (int e = 0; e < 8; ++e) v[e] = tile[col + e][rr];
        *(u16x8*)(xo + (size_t)rr * CIN + col) = v;
    }
}

// ---------------- K1: MFMA GEMM  pred[b][o][i] = W[o,:].xt[b,i,:] + Wb[o] ----------------
// block tile: 64 (o) x 256 (i); 4 waves, wave w covers i-range w*64; BK=64
__global__ __launch_bounds__(256) void k_gemm(const unsigned short* __restrict__ W,
                                              const float* __restrict__ Wb,
                                              const unsigned short* __restrict__ xt,
                                              unsigned short* __restrict__ pred) {
    __shared__ unsigned short As[64][72];    // [o][k]
    __shared__ unsigned short Bs[256][72];   // [i][k]
    int o0 = blockIdx.x * 64, i0 = blockIdx.y * 256, b = blockIdx.z;
    int t = threadIdx.x, w = t >> 6, l = t & 63;
    floatx4 acc[4][4] = {};  // [mt (o)][nt (i)]
    int srow = t >> 3, scol = (t & 7) * 8;
    const unsigned short* xb = xt + ((size_t)b * II + i0) * CIN;
    for (int kt = 0; kt < CIN; kt += 64) {
        __syncthreads();
#pragma unroll
        for (int r = 0; r < 2; ++r) {
            int rr = r * 32 + srow;
            *(u16x8*)&As[rr][scol] = *(const u16x8*)(W + (size_t)(o0 + rr) * CIN + kt + scol);
        }
#pragma unroll
        for (int r = 0; r < 8; ++r) {
            int rr = r * 32 + srow;
            *(u16x8*)&Bs[rr][scol] = *(const u16x8*)(xb + (size_t)rr * CIN + kt + scol);
        }
        __syncthreads();
        int lm = l & 15, lk = (l >> 4) * 8;
#pragma unroll
        for (int ks = 0; ks < 64; ks += 32) {
            short8 a[4], bf[4];
#pragma unroll
            for (int mt = 0; mt < 4; ++mt) a[mt] = *(const short8*)&As[mt * 16 + lm][ks + lk];
#pragma unroll
            for (int nt = 0; nt < 4; ++nt) bf[nt] = *(const short8*)&Bs[w * 64 + nt * 16 + lm][ks + lk];
#pragma unroll
            for (int mt = 0; mt < 4; ++mt)
#pragma unroll
                for (int nt = 0; nt < 4; ++nt)
                    acc[mt][nt] = __builtin_amdgcn_mfma_f32_16x16x32_bf16(a[mt], bf[nt], acc[mt][nt], 0, 0, 0);
        }
    }
    // epilogue: C[m=o][n=i]; lane: col=n=l&15, row=m=(l>>4)*4+reg
    int lm = l & 15, lg = l >> 4;
#pragma unroll
    for (int mt = 0; mt < 4; ++mt) {
#pragma unroll
        for (int r = 0; r < 4; ++r) {
            int o = o0 + mt * 16 + lg * 4 + r;
            float bias = Wb[o];
            size_t base = ((size_t)b * OO + o) << 10;
#pragma unroll
            for (int nt = 0; nt < 4; ++nt) {
                int i = i0 + w * 64 + nt * 16 + lm;
                pred[base + i] = f2b(acc[mt][nt][r] + bias);
            }
        }
    }
}

// ---------------- K1.5: s1[b,o] = 0.1 * sum_i pred[b,o,i]  (c1 uniform) ----------------
__global__ __launch_bounds__(256) void k_rowsum(const unsigned short* __restrict__ pred,
                                                float* __restrict__ s1) {
    int j = blockIdx.x, b = blockIdx.y, t = threadIdx.x;
    int d = t >> 3, seg = t & 7;
    const unsigned short* row = pred + (((size_t)b * OO + j * DD + d) << 10) + seg * 128;
    float s = 0.f;
    for (int ii = 0; ii < 128; ii += 8) {
        u16x8 u = *(const u16x8*)(row + ii);
#pragma unroll
        for (int e = 0; e < 8; ++e) s += b2f(u[e]);
    }
#pragma unroll
    for (int off = 4; off > 0; off >>= 1) s += __shfl_down(s, off, 8);
    if (seg == 0) s1[b * OO + j * DD + d] = 0.1f * s;
}

// ---------------- routing pass: squash(s_raw)->v; delta; softmax; partial s_next ----------------
// FIRST: logits = delta (b_prev = 0), write blog.  else: logits = blog + delta, no write.
template <bool FIRST>
__global__ __launch_bounds__(128) void k_route(const float* __restrict__ s_raw,
                                               const unsigned short* __restrict__ pred,
                                               float* __restrict__ blog,
                                               float* __restrict__ s_next) {
    __shared__ float s_lds[OO];
    __shared__ float v_lds[OO];
    __shared__ float cf[JJ];
    __shared__ float c_lds[JJ][128];
    int i0 = blockIdx.x * 128, b = blockIdx.y, t = threadIdx.x;
    for (int p = t; p < OO; p += 128) s_lds[p] = s_raw[b * OO + p];
    __syncthreads();
    if (t < JJ) {
        float n2 = 0.f;
#pragma unroll
        for (int d = 0; d < DD; ++d) { float v = s_lds[t * DD + d]; n2 += v * v; }
        cf[t] = sqrtf(n2) / (1.0f + n2);   // ||s||/(1+||s||^2)
    }
    __syncthreads();
    for (int p = t; p < OO; p += 128) v_lds[p] = s_lds[p] * cf[p >> 5];
    __syncthreads();

    int i = i0 + t;
    const unsigned short* pb = pred + (((size_t)b * OO) << 10) + i;
    float logit[JJ];
#pragma unroll
    for (int j = 0; j < JJ; ++j) {
        float dj = 0.f;
#pragma unroll
        for (int d = 0; d < DD; ++d)
            dj += v_lds[j * DD + d] * b2f(pb[(size_t)(j * DD + d) << 10]);
        if (FIRST) {
            blog[(size_t)(b * JJ + j) * II + i] = dj;
            logit[j] = dj;
        } else {
            logit[j] = blog[(size_t)(b * JJ + j) * II + i] + dj;
        }
    }
    float m = logit[0];
#pragma unroll
    for (int j = 1; j < JJ; ++j) m = fmaxf(m, logit[j]);
    float Z = 0.f, c[JJ];
#pragma unroll
    for (int j = 0; j < JJ; ++j) { c[j] = __expf(logit[j] - m); Z += c[j]; }
    float inv = 1.0f / Z;
#pragma unroll
    for (int j = 0; j < JJ; ++j) c_lds[j][t] = c[j] * inv;
    __syncthreads();
    // phase 2: s_next[b,p] += sum_{i in chunk} c[j][i] * pred[b,p,i],  p = j*32+d
    for (int p = t; p < OO; p += 128) {
        int j = p >> 5;
        const unsigned short* pr = pred + (((size_t)b * OO + p) << 10) + i0;
        float sum = 0.f;
        for (int ii = 0; ii < 128; ii += 8) {
            u16x8 u = *(const u16x8*)(pr + ii);
#pragma unroll
            for (int e = 0; e < 8; ++e) sum += c_lds[j][ii + e] * b2f(u[e]);
        }
        atomicAdd(&s_next[b * OO + p], sum);
    }
}

// ---------------- K4: out = squash(s3), f32 ----------------
__global__ __launch_bounds__(320) void k_final(const float* __restrict__ s_raw,
                                               float* __restrict__ out) {
    __shared__ float s_lds[OO];
    __shared__ float cf[JJ];
    int b = blockIdx.x, t = threadIdx.x;
    s_lds[t] = s_raw[b * OO + t];
    __syncthreads();
    if (t < JJ) {
        float n2 = 0.f;
#pragma unroll
        for (int d = 0; d < DD; ++d) { float v = s_lds[t * DD + d]; n2 += v * v; }
        cf[t] = sqrtf(n2) / (1.0f + n2);
    }
    __syncthreads();
    out[b * OO + t] = s_lds[t] * cf[t >> 5];
}

extern "C" void kernel_launch(void* const* d_in, const int* in_sizes, int n_in,
                              void* d_out, int out_size, void* d_ws, size_t ws_size,
                              hipStream_t stream) {
    const float* x  = (const float*)d_in[0];  // [64][256][1024] f32
    const float* W  = (const float*)d_in[1];  // [320][256] f32
    const float* Wb = (const float*)d_in[2];  // [320] f32

    char* ws = (char*)d_ws;
    unsigned short* xt   = (unsigned short*)(ws);              // 33,554,432 B
    unsigned short* pred = (unsigned short*)(ws + 33554432);   // 41,943,040 B -> ends 75,497,472
    unsigned short* Wbf  = (unsigned short*)(ws + 75497472);   // 163,840 B   -> ends 75,661,312
    float* s1 = (float*)(ws + 75661312);                       // 81,920 B
    float* s2 = (float*)(ws + 75661312 + 81920);               // 81,920 B
    float* s3 = (float*)(ws + 75661312 + 2 * 81920);           // 81,920 B
    float* b1 = (float*)(ws + 75661312 + 3 * 81920);           // 2,621,440 B
    // total: 78,528,512 B

    (void)hipMemsetAsync(s2, 0, 2 * 81920, stream);  // zero s2 and s3 (atomic accumulators)

    k_convW<<<80, 256, 0, stream>>>(W, Wbf);
    k_transpose<<<dim3(16, 4, BS), 256, 0, stream>>>(x, xt);
    k_gemm<<<dim3(5, 4, BS), 256, 0, stream>>>(Wbf, Wb, xt, pred);
    k_rowsum<<<dim3(JJ, BS), 256, 0, stream>>>(pred, s1);
    k_route<true><<<dim3(8, BS), 128, 0, stream>>>(s1, pred, b1, s2);
    k_route<false><<<dim3(8, BS), 128, 0, stream>>>(s2, pred, b1, s3);
    k_final<<<BS, 320, 0, stream>>>(s3, (float*)d_out);
}